// Round 4
// baseline (501.929 us; speedup 1.0000x reference)
//
#include <hip/hip_runtime.h>

// GCNConv forward on MI355X — bucketed (radix-by-dst) aggregation, no global
// f32 atomics, no node-granular CSR.
// N=65536, E=1048576, D=64.  Bucket = dst>>6 (1024 buckets of 64 nodes).
//
//   hist     : bucket counts (LDS-pre-reduced)
//   scan     : bucket_base = exclusive prefix; cursors (cacheline-padded)
//   scatter  : packed[pos] = (dst&63)<<16 | src   (bucket-sequential writes)
//   deg/dinv : per-bucket LDS count -> dinv = rsqrt(1+indeg)
//   gemm     : g = (x @ W) * dinv[row]
//   agg      : per bucket: LDS acc[64][64]; init with self term g[node];
//              += g[src] via LDS f32 atomics; out = acc*dinv + b (float4)
//
// R4 fix: bbase[1024] previously overlapped cursor[0] (layout bug) -> bucket 0
// scattered past `packed` and aggregated poisoned data. bbase now has its own
// 8 KB slot.

#define N_DIM 64
#define NBUCK 1024
#define CUR_STRIDE 16   // one 64B line per cursor

__global__ void k_zero(unsigned* __restrict__ p, int n) {
    int i = blockIdx.x * blockDim.x + threadIdx.x;
    if (i < n) p[i] = 0u;
}

__global__ void k_hist(const int* __restrict__ dst, unsigned* __restrict__ bcnt, int E) {
    __shared__ unsigned h[NBUCK];
    for (int i = threadIdx.x; i < NBUCK; i += blockDim.x) h[i] = 0u;
    __syncthreads();
    int stride = gridDim.x * blockDim.x;
    for (int e = blockIdx.x * blockDim.x + threadIdx.x; e < E; e += stride)
        atomicAdd(&h[((unsigned)dst[e]) >> 6], 1u);
    __syncthreads();
    for (int i = threadIdx.x; i < NBUCK; i += blockDim.x) {
        unsigned v = h[i];
        if (v) atomicAdd(&bcnt[i], v);
    }
}

__global__ void k_scan_buckets(const unsigned* __restrict__ bcnt, unsigned* __restrict__ bbase,
                               unsigned* __restrict__ cursor) {
    __shared__ unsigned s[NBUCK];
    int t = threadIdx.x;
    unsigned v = bcnt[t];
    s[t] = v;
    __syncthreads();
    for (int off = 1; off < NBUCK; off <<= 1) {
        unsigned u = (t >= off) ? s[t - off] : 0u;
        __syncthreads();
        s[t] += u;
        __syncthreads();
    }
    unsigned excl = s[t] - v;
    bbase[t] = excl;
    cursor[t * CUR_STRIDE] = excl;
    if (t == NBUCK - 1) bbase[NBUCK] = s[t];
}

__global__ void k_scatter_pack(const int* __restrict__ src, const int* __restrict__ dst,
                               unsigned* __restrict__ cursor, unsigned* __restrict__ packed, int E) {
    int e = blockIdx.x * blockDim.x + threadIdx.x;
    if (e >= E) return;
    unsigned s = (unsigned)src[e], d = (unsigned)dst[e];
    unsigned bkt = d >> 6;
    unsigned pos = atomicAdd(&cursor[bkt * CUR_STRIDE], 1u);
    packed[pos] = ((d & 63u) << 16) | s;
}

__global__ void k_deg_dinv(const unsigned* __restrict__ packed, const unsigned* __restrict__ bbase,
                           float* __restrict__ dinv) {
    __shared__ unsigned h[64];
    int b = blockIdx.x, t = threadIdx.x;
    if (t < 64) h[t] = 0u;
    __syncthreads();
    unsigned s0 = bbase[b], s1 = bbase[b + 1];
    for (unsigned k = s0 + t; k < s1; k += blockDim.x) atomicAdd(&h[packed[k] >> 16], 1u);
    __syncthreads();
    if (t < 64) dinv[b * 64 + t] = rsqrtf((float)(h[t] + 1u));  // +1 self-loop
}

// g = (x @ W) * dinv[row].  32 rows per 256-thread block; W^T in padded LDS.
__global__ void k_gemm_g(const float* __restrict__ x, const float* __restrict__ W,
                         const float* __restrict__ dinv, float* __restrict__ g, int nrows) {
    __shared__ float sX[32 * 64];
    __shared__ float sWt[64 * 65];
    int tid = threadIdx.x;
    for (int idx = tid; idx < 64 * 64; idx += 256) {
        int k = idx >> 6, c = idx & 63;
        sWt[c * 65 + k] = W[k * 64 + c];
    }
    const float4* x4p = (const float4*)(x + (size_t)blockIdx.x * 32 * 64);
    float4* sX4 = (float4*)sX;
    sX4[tid]       = x4p[tid];
    sX4[tid + 256] = x4p[tid + 256];
    __syncthreads();

    int c  = tid & 63;
    int rg = tid >> 6;
    int row0 = blockIdx.x * 32 + rg * 8;
    float acc[8];
#pragma unroll
    for (int r = 0; r < 8; ++r) acc[r] = 0.f;
    for (int k = 0; k < 64; k += 4) {
        float4 w4 = *(const float4*)&sWt[c * 65 + k];
#pragma unroll
        for (int r = 0; r < 8; ++r) {
            float4 x4 = *(const float4*)&sX[(rg * 8 + r) * 64 + k];
            acc[r] = fmaf(x4.x, w4.x, acc[r]);
            acc[r] = fmaf(x4.y, w4.y, acc[r]);
            acc[r] = fmaf(x4.z, w4.z, acc[r]);
            acc[r] = fmaf(x4.w, w4.w, acc[r]);
        }
    }
#pragma unroll
    for (int r = 0; r < 8; ++r) {
        int row = row0 + r;
        g[(size_t)row * 64 + c] = acc[r] * dinv[row];
    }
}

// One block per bucket (64 nodes). 512 threads = 8 waves, lane = channel.
__global__ void __launch_bounds__(512) k_bucket_agg(
        const float* __restrict__ g, const unsigned* __restrict__ packed,
        const unsigned* __restrict__ bbase, const float* __restrict__ dinv,
        const float* __restrict__ bias, float* __restrict__ out) {
    __shared__ float acc[64 * N_DIM];   // 16 KB
    int b = blockIdx.x, tid = threadIdx.x;
    int c = tid & 63, w = tid >> 6;

    // init with self-loop term: acc[l][c] = g[(b*64+l)*64+c]
    float4* a4 = (float4*)acc;
    const float4* g4 = (const float4*)(g + (size_t)b * 64 * N_DIM);
    a4[tid]       = g4[tid];
    a4[tid + 512] = g4[tid + 512];
    __syncthreads();

    unsigned s0 = bbase[b], s1 = bbase[b + 1];
    unsigned cnt = s1 - s0;
    unsigned len = (cnt + 7u) >> 3;
    unsigned ks = s0 + (unsigned)w * len;
    if (ks > s1) ks = s1;
    unsigned ke = ks + len;
    if (ke > s1) ke = s1;

    unsigned k = ks;
    for (; k + 4 <= ke; k += 4) {
        unsigned p0 = packed[k], p1 = packed[k + 1], p2 = packed[k + 2], p3 = packed[k + 3];
        float v0 = g[(size_t)(p0 & 0xFFFFu) * N_DIM + c];
        float v1 = g[(size_t)(p1 & 0xFFFFu) * N_DIM + c];
        float v2 = g[(size_t)(p2 & 0xFFFFu) * N_DIM + c];
        float v3 = g[(size_t)(p3 & 0xFFFFu) * N_DIM + c];
        atomicAdd(&acc[(p0 >> 16) * N_DIM + c], v0);
        atomicAdd(&acc[(p1 >> 16) * N_DIM + c], v1);
        atomicAdd(&acc[(p2 >> 16) * N_DIM + c], v2);
        atomicAdd(&acc[(p3 >> 16) * N_DIM + c], v3);
    }
    for (; k < ke; ++k) {
        unsigned p = packed[k];
        atomicAdd(&acc[(p >> 16) * N_DIM + c], g[(size_t)(p & 0xFFFFu) * N_DIM + c]);
    }
    __syncthreads();

    // out = acc * dinv + bias   (float4, coalesced)
    float4* o4 = (float4*)(out + (size_t)b * 64 * N_DIM);
    const float4* b4 = (const float4*)bias;
    for (int i = tid; i < 1024; i += 512) {
        int l = i >> 4, c4 = i & 15;
        float4 a = a4[i];
        float dv = dinv[b * 64 + l];
        float4 bb = b4[c4];
        float4 r;
        r.x = a.x * dv + bb.x; r.y = a.y * dv + bb.y;
        r.z = a.z * dv + bb.z; r.w = a.w * dv + bb.w;
        o4[i] = r;
    }
}

extern "C" void kernel_launch(void* const* d_in, const int* in_sizes, int n_in,
                              void* d_out, int out_size, void* d_ws, size_t ws_size,
                              hipStream_t stream) {
    const float* x  = (const float*)d_in[0];
    const int*   ei = (const int*)d_in[1];
    const float* W  = (const float*)d_in[2];
    const float* b  = (const float*)d_in[3];
    float*       out = (float*)d_out;

    const int N = in_sizes[0] / N_DIM;   // 65536
    const int E = in_sizes[1] / 2;       // 1048576
    const int* src = ei;
    const int* dst = ei + E;

    // Workspace layout (bytes) — every region gets a private, padded slot:
    //   bcnt   u32[1024]        @ 0        (4 KB)
    //   bbase  u32[1025]        @ 4096     (8 KB slot — fix for R3 overlap)
    //   cursor u32[1024*16]     @ 12288    (64 KB, line-padded)
    //   dinv   f32[N]           @ 77824    (256 KB)
    //   packed u32[E]           @ 339968   (4 MB)
    //   g      f32[N*64]        @ 339968 + 4*E   (16 MB; total ~20.3 MB)
    char* ws = (char*)d_ws;
    unsigned* bcnt   = (unsigned*)(ws);
    unsigned* bbase  = (unsigned*)(ws + 4096);
    unsigned* cursor = (unsigned*)(ws + 12288);
    float*    dinv   = (float*)   (ws + 77824);
    unsigned* packed = (unsigned*)(ws + 339968);
    float*    g      = (float*)   (ws + 339968 + (size_t)E * 4);

    k_zero        <<<NBUCK / 256, 256, 0, stream>>>(bcnt, NBUCK);
    k_hist        <<<512, 256, 0, stream>>>(dst, bcnt, E);
    k_scan_buckets<<<1, NBUCK, 0, stream>>>(bcnt, bbase, cursor);
    k_scatter_pack<<<(E + 255) / 256, 256, 0, stream>>>(src, dst, cursor, packed, E);
    k_deg_dinv    <<<NBUCK, 256, 0, stream>>>(packed, bbase, dinv);
    k_gemm_g      <<<N / 32, 256, 0, stream>>>(x, W, dinv, g, N);
    k_bucket_agg  <<<NBUCK, 512, 0, stream>>>(g, packed, bbase, dinv, b, out);
}

// Round 5
// 211.185 us; speedup vs baseline: 2.3767x; 2.3767x over previous
//
#include <hip/hip_runtime.h>

// GCNConv forward on MI355X — bucket radix + within-bucket counting sort ->
// node-level CSR -> register-accumulating pull (no atomics in the hot kernel).
// N=65536, E=1048576, D=64.  Bucket = dst>>6 (1024 buckets of 64 nodes).
//
//   hist       : bucket counts (LDS-pre-reduced)
//   scan       : bucket_base = exclusive prefix; line-padded cursors
//   scatter    : packed[pos] = (dst&63)<<16 | src   (bucket-local writes)
//   sort_nodes : per bucket, counting-sort by node -> csr2 (src ids, node-
//                contiguous); emits row_start[node] and dinv[node]
//   gemm       : g = (x @ W) * dinv[row]
//   pull       : one wave per node, lane=channel, 8-deep gather ILP,
//                out = (g_self + sum g_src) * dinv + b   (single write)

#define N_DIM 64
#define NBUCK 1024
#define CUR_STRIDE 16   // one 64B line per bucket cursor

__global__ void k_zero(unsigned* __restrict__ p, int n) {
    int i = blockIdx.x * blockDim.x + threadIdx.x;
    if (i < n) p[i] = 0u;
}

__global__ void k_hist(const int* __restrict__ dst, unsigned* __restrict__ bcnt, int E) {
    __shared__ unsigned h[NBUCK];
    for (int i = threadIdx.x; i < NBUCK; i += blockDim.x) h[i] = 0u;
    __syncthreads();
    int stride = gridDim.x * blockDim.x;
    for (int e = blockIdx.x * blockDim.x + threadIdx.x; e < E; e += stride)
        atomicAdd(&h[((unsigned)dst[e]) >> 6], 1u);
    __syncthreads();
    for (int i = threadIdx.x; i < NBUCK; i += blockDim.x) {
        unsigned v = h[i];
        if (v) atomicAdd(&bcnt[i], v);
    }
}

__global__ void k_scan_buckets(const unsigned* __restrict__ bcnt, unsigned* __restrict__ bbase,
                               unsigned* __restrict__ cursor, unsigned* __restrict__ row_start,
                               int N, int E) {
    __shared__ unsigned s[NBUCK];
    int t = threadIdx.x;
    unsigned v = bcnt[t];
    s[t] = v;
    __syncthreads();
    for (int off = 1; off < NBUCK; off <<= 1) {
        unsigned u = (t >= off) ? s[t - off] : 0u;
        __syncthreads();
        s[t] += u;
        __syncthreads();
    }
    unsigned excl = s[t] - v;
    bbase[t] = excl;
    cursor[t * CUR_STRIDE] = excl;
    if (t == NBUCK - 1) {
        bbase[NBUCK] = s[t];
        row_start[N] = (unsigned)E;   // global sentinel for k_pull's row_end
    }
}

__global__ void k_scatter_pack(const int* __restrict__ src, const int* __restrict__ dst,
                               unsigned* __restrict__ cursor, unsigned* __restrict__ packed, int E) {
    int e = blockIdx.x * blockDim.x + threadIdx.x;
    if (e >= E) return;
    unsigned s = (unsigned)src[e], d = (unsigned)dst[e];
    unsigned bkt = d >> 6;
    unsigned pos = atomicAdd(&cursor[bkt * CUR_STRIDE], 1u);
    packed[pos] = ((d & 63u) << 16) | s;
}

// One block per bucket: counting-sort the bucket's edges by node (dst&63).
// Pass 1 counts, serial 64-entry scan, pass 2 scatters src ids into csr2
// (node-contiguous within the bucket region). Also emits row_start and dinv.
__global__ void k_sort_nodes(const unsigned* __restrict__ packed, const unsigned* __restrict__ bbase,
                             unsigned* __restrict__ csr2, unsigned* __restrict__ row_start,
                             float* __restrict__ dinv) {
    __shared__ unsigned cnt[64];
    __shared__ unsigned cur[64];
    int b = blockIdx.x, t = threadIdx.x;
    if (t < 64) cnt[t] = 0u;
    __syncthreads();
    unsigned s0 = bbase[b], s1 = bbase[b + 1];
    for (unsigned k = s0 + t; k < s1; k += blockDim.x) atomicAdd(&cnt[packed[k] >> 16], 1u);
    __syncthreads();
    if (t == 0) {
        unsigned run = 0;
        for (int j = 0; j < 64; ++j) { cur[j] = run; run += cnt[j]; }
    }
    __syncthreads();
    if (t < 64) {
        row_start[b * 64 + t] = s0 + cur[t];
        dinv[b * 64 + t] = rsqrtf((float)(cnt[t] + 1u));   // +1 self-loop
    }
    __syncthreads();
    for (unsigned k = s0 + t; k < s1; k += blockDim.x) {
        unsigned p = packed[k];
        unsigned pos = s0 + atomicAdd(&cur[p >> 16], 1u);
        csr2[pos] = p & 0xFFFFu;
    }
}

// g = (x @ W) * dinv[row].  32 rows per 256-thread block; W^T in padded LDS.
__global__ void k_gemm_g(const float* __restrict__ x, const float* __restrict__ W,
                         const float* __restrict__ dinv, float* __restrict__ g, int nrows) {
    __shared__ float sX[32 * 64];
    __shared__ float sWt[64 * 65];
    int tid = threadIdx.x;
    for (int idx = tid; idx < 64 * 64; idx += 256) {
        int k = idx >> 6, c = idx & 63;
        sWt[c * 65 + k] = W[k * 64 + c];
    }
    const float4* x4p = (const float4*)(x + (size_t)blockIdx.x * 32 * 64);
    float4* sX4 = (float4*)sX;
    sX4[tid]       = x4p[tid];
    sX4[tid + 256] = x4p[tid + 256];
    __syncthreads();

    int c  = tid & 63;
    int rg = tid >> 6;
    int row0 = blockIdx.x * 32 + rg * 8;
    float acc[8];
#pragma unroll
    for (int r = 0; r < 8; ++r) acc[r] = 0.f;
    for (int k = 0; k < 64; k += 4) {
        float4 w4 = *(const float4*)&sWt[c * 65 + k];
#pragma unroll
        for (int r = 0; r < 8; ++r) {
            float4 x4 = *(const float4*)&sX[(rg * 8 + r) * 64 + k];
            acc[r] = fmaf(x4.x, w4.x, acc[r]);
            acc[r] = fmaf(x4.y, w4.y, acc[r]);
            acc[r] = fmaf(x4.z, w4.z, acc[r]);
            acc[r] = fmaf(x4.w, w4.w, acc[r]);
        }
    }
#pragma unroll
    for (int r = 0; r < 8; ++r) {
        int row = row0 + r;
        g[(size_t)row * 64 + c] = acc[r] * dinv[row];
    }
}

// One wave per node, lane = channel, register accumulation, 8-deep gather ILP.
__global__ void k_pull(const float* __restrict__ g, const unsigned* __restrict__ row_start,
                       const unsigned* __restrict__ csr2, const float* __restrict__ dinv,
                       const float* __restrict__ bias, float* __restrict__ out, int n) {
    int node = blockIdx.x * 4 + (threadIdx.x >> 6);
    if (node >= n) return;
    int c = threadIdx.x & 63;
    unsigned k  = row_start[node];
    unsigned k1 = row_start[node + 1];
    float acc = g[(size_t)node * N_DIM + c];   // self-loop term (g = h*dinv)
    for (; k + 8 <= k1; k += 8) {
        unsigned i0 = csr2[k],     i1 = csr2[k + 1], i2 = csr2[k + 2], i3 = csr2[k + 3];
        unsigned i4 = csr2[k + 4], i5 = csr2[k + 5], i6 = csr2[k + 6], i7 = csr2[k + 7];
        float v0 = g[(size_t)i0 * N_DIM + c];
        float v1 = g[(size_t)i1 * N_DIM + c];
        float v2 = g[(size_t)i2 * N_DIM + c];
        float v3 = g[(size_t)i3 * N_DIM + c];
        float v4 = g[(size_t)i4 * N_DIM + c];
        float v5 = g[(size_t)i5 * N_DIM + c];
        float v6 = g[(size_t)i6 * N_DIM + c];
        float v7 = g[(size_t)i7 * N_DIM + c];
        acc += v0; acc += v1; acc += v2; acc += v3;
        acc += v4; acc += v5; acc += v6; acc += v7;
    }
    for (; k < k1; ++k) acc += g[(size_t)csr2[k] * N_DIM + c];
    out[(size_t)node * N_DIM + c] = acc * dinv[node] + bias[c];
}

extern "C" void kernel_launch(void* const* d_in, const int* in_sizes, int n_in,
                              void* d_out, int out_size, void* d_ws, size_t ws_size,
                              hipStream_t stream) {
    const float* x  = (const float*)d_in[0];
    const int*   ei = (const int*)d_in[1];
    const float* W  = (const float*)d_in[2];
    const float* b  = (const float*)d_in[3];
    float*       out = (float*)d_out;

    const int N = in_sizes[0] / N_DIM;   // 65536
    const int E = in_sizes[1] / 2;       // 1048576
    const int* src = ei;
    const int* dst = ei + E;

    // Workspace layout (bytes), private padded slots:
    //   bcnt      u32[1024]       @ 0         (4 KB)
    //   bbase     u32[1025]       @ 4096      (8 KB slot)
    //   cursor    u32[1024*16]    @ 12288     (64 KB)
    //   dinv      f32[N]          @ 77824     (256 KB)
    //   row_start u32[N+1]        @ 339968    (260 KB slot)
    //   packed    u32[E]          @ 606208    (4 MB)
    //   csr2      u32[E]          @ 4800512   (4 MB)
    //   g         f32[N*64]       @ 8994816   (16 MB)   total ~24.6 MB
    char* ws = (char*)d_ws;
    unsigned* bcnt      = (unsigned*)(ws);
    unsigned* bbase     = (unsigned*)(ws + 4096);
    unsigned* cursor    = (unsigned*)(ws + 12288);
    float*    dinv      = (float*)   (ws + 77824);
    unsigned* row_start = (unsigned*)(ws + 339968);
    unsigned* packed    = (unsigned*)(ws + 606208);
    unsigned* csr2      = (unsigned*)(ws + 4800512);
    float*    g         = (float*)   (ws + 8994816);

    k_zero        <<<NBUCK / 256, 256, 0, stream>>>(bcnt, NBUCK);
    k_hist        <<<512, 256, 0, stream>>>(dst, bcnt, E);
    k_scan_buckets<<<1, NBUCK, 0, stream>>>(bcnt, bbase, cursor, row_start, N, E);
    k_scatter_pack<<<(E + 255) / 256, 256, 0, stream>>>(src, dst, cursor, packed, E);
    k_sort_nodes  <<<NBUCK, 256, 0, stream>>>(packed, bbase, csr2, row_start, dinv);
    k_gemm_g      <<<N / 32, 256, 0, stream>>>(x, W, dinv, g, N);
    k_pull        <<<(N + 3) / 4, 256, 0, stream>>>(g, row_start, csr2, dinv, b, out, N);
}

// Round 6
// 199.502 us; speedup vs baseline: 2.5159x; 1.0586x over previous
//
#include <hip/hip_runtime.h>

// GCNConv forward on MI355X — bucket radix (XCD-partitioned scatter) +
// within-bucket counting sort -> node CSR -> bf16-gather register pull.
// N=65536, E=1048576, D=64.  Bucket = dst>>6 (1024 buckets of 64 nodes).
//
// R6: (1) scatter replicated 8x, partition p = blockIdx&7 writes only buckets
//     with bkt>>7 == p  -> all writes to a packed line come from one XCD's L2
//     (full-line writebacks; R5 saw 54 MB HBM writes for a 4 MB payload).
//     (2) g stored as bf16 (RNE): halves the 268 MB gather demand in k_pull.
//         Pull: lane = channel-pair, halves of the wave take alternate edges,
//         cross-half shfl_xor reduce, fp32 accumulation.

#define N_DIM 64
#define NBUCK 1024
#define CUR_STRIDE 16   // one 64B line per bucket cursor
#define NSLICE 512      // edge slices for the partitioned scatter

__global__ void k_zero(unsigned* __restrict__ p, int n) {
    int i = blockIdx.x * blockDim.x + threadIdx.x;
    if (i < n) p[i] = 0u;
}

__global__ void k_hist(const int* __restrict__ dst, unsigned* __restrict__ bcnt, int E) {
    __shared__ unsigned h[NBUCK];
    for (int i = threadIdx.x; i < NBUCK; i += blockDim.x) h[i] = 0u;
    __syncthreads();
    int stride = gridDim.x * blockDim.x;
    for (int e = blockIdx.x * blockDim.x + threadIdx.x; e < E; e += stride)
        atomicAdd(&h[((unsigned)dst[e]) >> 6], 1u);
    __syncthreads();
    for (int i = threadIdx.x; i < NBUCK; i += blockDim.x) {
        unsigned v = h[i];
        if (v) atomicAdd(&bcnt[i], v);
    }
}

__global__ void k_scan_buckets(const unsigned* __restrict__ bcnt, unsigned* __restrict__ bbase,
                               unsigned* __restrict__ cursor, unsigned* __restrict__ row_start,
                               int N, int E) {
    __shared__ unsigned s[NBUCK];
    int t = threadIdx.x;
    unsigned v = bcnt[t];
    s[t] = v;
    __syncthreads();
    for (int off = 1; off < NBUCK; off <<= 1) {
        unsigned u = (t >= off) ? s[t - off] : 0u;
        __syncthreads();
        s[t] += u;
        __syncthreads();
    }
    unsigned excl = s[t] - v;
    bbase[t] = excl;
    cursor[t * CUR_STRIDE] = excl;
    if (t == NBUCK - 1) {
        bbase[NBUCK] = s[t];
        row_start[N] = (unsigned)E;
    }
}

// Partitioned scatter: blockIdx&7 = partition (assumed XCD via round-robin);
// each partition scans all edges in its slice, keeps buckets with bkt>>7==p.
__global__ void k_scatter_pack(const int* __restrict__ src, const int* __restrict__ dst,
                               unsigned* __restrict__ cursor, unsigned* __restrict__ packed, int E) {
    unsigned p     = blockIdx.x & 7u;
    unsigned slice = blockIdx.x >> 3;
    int chunk = (E + NSLICE - 1) / NSLICE;
    int e0 = slice * chunk;
    int e1 = e0 + chunk; if (e1 > E) e1 = E;
    for (int e = e0 + threadIdx.x; e < e1; e += blockDim.x) {
        unsigned d = (unsigned)dst[e];
        unsigned s = (unsigned)src[e];
        unsigned bkt = d >> 6;
        if ((bkt >> 7) == p) {
            unsigned pos = atomicAdd(&cursor[bkt * CUR_STRIDE], 1u);
            packed[pos] = ((d & 63u) << 16) | s;
        }
    }
}

// One block per bucket (blockIdx swizzled so reader XCD == writer XCD):
// counting-sort the bucket's edges by node (dst&63) -> csr2; emit row_start, dinv.
__global__ void k_sort_nodes(const unsigned* __restrict__ packed, const unsigned* __restrict__ bbase,
                             unsigned* __restrict__ csr2, unsigned* __restrict__ row_start,
                             float* __restrict__ dinv) {
    __shared__ unsigned cnt[64];
    __shared__ unsigned cur[64];
    int b = (int)(((blockIdx.x & 7u) << 7) | (blockIdx.x >> 3));  // bkt>>7 == blockIdx&7
    int t = threadIdx.x;
    if (t < 64) cnt[t] = 0u;
    __syncthreads();
    unsigned s0 = bbase[b], s1 = bbase[b + 1];
    for (unsigned k = s0 + t; k < s1; k += blockDim.x) atomicAdd(&cnt[packed[k] >> 16], 1u);
    __syncthreads();
    if (t == 0) {
        unsigned run = 0;
        for (int j = 0; j < 64; ++j) { cur[j] = run; run += cnt[j]; }
    }
    __syncthreads();
    if (t < 64) {
        row_start[b * 64 + t] = s0 + cur[t];
        dinv[b * 64 + t] = rsqrtf((float)(cnt[t] + 1u));   // +1 self-loop
    }
    __syncthreads();
    for (unsigned k = s0 + t; k < s1; k += blockDim.x) {
        unsigned p = packed[k];
        unsigned pos = s0 + atomicAdd(&cur[p >> 16], 1u);
        csr2[pos] = p & 0xFFFFu;
    }
}

// g = bf16( (x @ W) * dinv[row] ), RNE.  32 rows per 256-thread block.
__global__ void k_gemm_g(const float* __restrict__ x, const float* __restrict__ W,
                         const float* __restrict__ dinv, unsigned short* __restrict__ g2s,
                         int nrows) {
    __shared__ float sX[32 * 64];
    __shared__ float sWt[64 * 65];
    int tid = threadIdx.x;
    for (int idx = tid; idx < 64 * 64; idx += 256) {
        int k = idx >> 6, c = idx & 63;
        sWt[c * 65 + k] = W[k * 64 + c];
    }
    const float4* x4p = (const float4*)(x + (size_t)blockIdx.x * 32 * 64);
    float4* sX4 = (float4*)sX;
    sX4[tid]       = x4p[tid];
    sX4[tid + 256] = x4p[tid + 256];
    __syncthreads();

    int c  = tid & 63;
    int rg = tid >> 6;
    int row0 = blockIdx.x * 32 + rg * 8;
    float acc[8];
#pragma unroll
    for (int r = 0; r < 8; ++r) acc[r] = 0.f;
    for (int k = 0; k < 64; k += 4) {
        float4 w4 = *(const float4*)&sWt[c * 65 + k];
#pragma unroll
        for (int r = 0; r < 8; ++r) {
            float4 x4 = *(const float4*)&sX[(rg * 8 + r) * 64 + k];
            acc[r] = fmaf(x4.x, w4.x, acc[r]);
            acc[r] = fmaf(x4.y, w4.y, acc[r]);
            acc[r] = fmaf(x4.z, w4.z, acc[r]);
            acc[r] = fmaf(x4.w, w4.w, acc[r]);
        }
    }
#pragma unroll
    for (int r = 0; r < 8; ++r) {
        int row = row0 + r;
        float v = acc[r] * dinv[row];
        unsigned bu = __float_as_uint(v);
        bu += 0x7FFFu + ((bu >> 16) & 1u);            // RNE to bf16
        g2s[(size_t)row * 64 + c] = (unsigned short)(bu >> 16);
    }
}

// One wave per node. lane = (half h, channel-pair ch2). Halves take blocks of
// 4 consecutive edges (8 edges per wave-iter, 4-deep gather ILP per half).
// fp32 accumulate, cross-half shfl_xor(32) reduce, self term + bias + scale.
__global__ void k_pull(const unsigned* __restrict__ g2u, const unsigned* __restrict__ row_start,
                       const unsigned* __restrict__ csr2, const float* __restrict__ dinv,
                       const float* __restrict__ bias, float* __restrict__ out, int n) {
    int node = blockIdx.x * 4 + (threadIdx.x >> 6);
    if (node >= n) return;
    int lane = threadIdx.x & 63;
    int h   = lane >> 5;
    int ch2 = lane & 31;
    unsigned k  = row_start[node];
    unsigned k1 = row_start[node + 1];
    float ax = 0.f, ay = 0.f;
    for (; k + 8 <= k1; k += 8) {
        unsigned base = k + (unsigned)(h << 2);
        unsigned i0 = csr2[base], i1 = csr2[base + 1];
        unsigned i2 = csr2[base + 2], i3 = csr2[base + 3];
        unsigned u0 = g2u[(size_t)i0 * 32 + ch2];
        unsigned u1 = g2u[(size_t)i1 * 32 + ch2];
        unsigned u2 = g2u[(size_t)i2 * 32 + ch2];
        unsigned u3 = g2u[(size_t)i3 * 32 + ch2];
        ax += __uint_as_float(u0 << 16); ay += __uint_as_float(u0 & 0xFFFF0000u);
        ax += __uint_as_float(u1 << 16); ay += __uint_as_float(u1 & 0xFFFF0000u);
        ax += __uint_as_float(u2 << 16); ay += __uint_as_float(u2 & 0xFFFF0000u);
        ax += __uint_as_float(u3 << 16); ay += __uint_as_float(u3 & 0xFFFF0000u);
    }
    for (unsigned e = k + (unsigned)h; e < k1; e += 2) {
        unsigned u = g2u[(size_t)csr2[e] * 32 + ch2];
        ax += __uint_as_float(u << 16); ay += __uint_as_float(u & 0xFFFF0000u);
    }
    ax += __shfl_xor(ax, 32);
    ay += __shfl_xor(ay, 32);
    unsigned su = g2u[(size_t)node * 32 + ch2];   // self-loop term
    ax += __uint_as_float(su << 16);
    ay += __uint_as_float(su & 0xFFFF0000u);
    float dv = dinv[node];
    if (h == 0) {
        float2 r;
        r.x = ax * dv + bias[ch2 * 2];
        r.y = ay * dv + bias[ch2 * 2 + 1];
        *(float2*)(out + (size_t)node * N_DIM + ch2 * 2) = r;
    }
}

extern "C" void kernel_launch(void* const* d_in, const int* in_sizes, int n_in,
                              void* d_out, int out_size, void* d_ws, size_t ws_size,
                              hipStream_t stream) {
    const float* x  = (const float*)d_in[0];
    const int*   ei = (const int*)d_in[1];
    const float* W  = (const float*)d_in[2];
    const float* b  = (const float*)d_in[3];
    float*       out = (float*)d_out;

    const int N = in_sizes[0] / N_DIM;   // 65536
    const int E = in_sizes[1] / 2;       // 1048576
    const int* src = ei;
    const int* dst = ei + E;

    // Workspace layout (bytes), private padded slots:
    //   bcnt      u32[1024]       @ 0         (4 KB)
    //   bbase     u32[1025]       @ 4096      (8 KB slot)
    //   cursor    u32[1024*16]    @ 12288     (64 KB)
    //   dinv      f32[N]          @ 77824     (256 KB)
    //   row_start u32[N+1]        @ 339968    (260 KB slot)
    //   packed    u32[E]          @ 606208    (4 MB)
    //   csr2      u32[E]          @ 4800512   (4 MB)
    //   g (bf16)  u16[N*64]       @ 8994816   (8 MB)   total ~17 MB
    char* ws = (char*)d_ws;
    unsigned* bcnt      = (unsigned*)(ws);
    unsigned* bbase     = (unsigned*)(ws + 4096);
    unsigned* cursor    = (unsigned*)(ws + 12288);
    float*    dinv      = (float*)   (ws + 77824);
    unsigned* row_start = (unsigned*)(ws + 339968);
    unsigned* packed    = (unsigned*)(ws + 606208);
    unsigned* csr2      = (unsigned*)(ws + 4800512);
    unsigned short* g2s = (unsigned short*)(ws + 8994816);
    unsigned*       g2u = (unsigned*)(ws + 8994816);

    k_zero        <<<NBUCK / 256, 256, 0, stream>>>(bcnt, NBUCK);
    k_hist        <<<512, 256, 0, stream>>>(dst, bcnt, E);
    k_scan_buckets<<<1, NBUCK, 0, stream>>>(bcnt, bbase, cursor, row_start, N, E);
    k_scatter_pack<<<8 * NSLICE, 256, 0, stream>>>(src, dst, cursor, packed, E);
    k_sort_nodes  <<<NBUCK, 256, 0, stream>>>(packed, bbase, csr2, row_start, dinv);
    k_gemm_g      <<<N / 32, 256, 0, stream>>>(x, W, dinv, g2s, N);
    k_pull        <<<(N + 3) / 4, 256, 0, stream>>>(g2u, row_start, csr2, dinv, b, out, N);
}